// Round 7
// baseline (172.558 us; speedup 1.0000x reference)
//
#include <hip/hip_runtime.h>
#include <hip/hip_bf16.h>

// ---------------------------------------------------------------------------
//   x_e  [2,128,24,24,24]   pred [2,32,96,96,96]   out [2,3,96,96,96] fp32
//   conv(128->256,k3,s2,VALID) -> 11^3 positions; mean∘conv commutes, so
//   conv+pool collapses to 27 window-sums per channel (exact).
//   K_A (256 blocks, 5 spin barriers): stats+prefetch -> winsum -> xfeat ->
//   ctrl1 -> ctrl2 -> ctrl3.   K_B (1728 blocks): seg streaming op.
// ---------------------------------------------------------------------------

#define P4 221184        // 96^3/4

typedef float v4f __attribute__((ext_vector_type(4)));

// ws float offsets
#define WS_STATSPART 0       // 256 x float2 = 512
#define WS_WINS      512     // [2][128][27] = 6912
#define WS_XF        7424    // 512
#define WS_P         7936    // 6*512
#define WS_C         11008   // 6*256
#define WS_EFFW      12544   // 192
#define WS_BAR       12736   // 2 ints
#define WS_SINK      12740

// Generation-based spin barrier among nb co-resident blocks.
// bar[0]=count (zeroed by host memset each replay), bar[1]=generation.
__device__ __forceinline__ void spin_barrier(int* bar, int nb) {
  __syncthreads();
  if (threadIdx.x == 0) {
    __threadfence();                       // release prior writes
    int gen = atomicAdd(&bar[1], 0);
    int old = atomicAdd(&bar[0], 1);
    if (old == nb - 1) {
      atomicExch(&bar[0], 0);
      __threadfence();
      atomicAdd(&bar[1], 1);               // release
    } else {
      while (atomicAdd(&bar[1], 0) == gen) __builtin_amdgcn_s_sleep(8);
    }
    __threadfence();                       // acquire
  }
  __syncthreads();
}

// ---------------------------------------------------------------------------
// K_A: the whole pre-chain on 256 blocks (1 per CU; co-residency guaranteed:
// 55.7 KB LDS, 256-thread blocks).  Note: stats chunk blk == channel slice
// (b,c)=blk (both 13824 floats at x_e + blk*13824).
// ---------------------------------------------------------------------------
__global__ __launch_bounds__(256) void chain_kernel(
    const float* __restrict__ x_e,
    const float* __restrict__ gn_g, const float* __restrict__ gn_b,
    const float* __restrict__ gap_w, const float* __restrict__ gap_b,
    const float* __restrict__ w_cf,  const float* __restrict__ b_cf,
    const float* __restrict__ w_c,   const float* __restrict__ b_c,
    const float* __restrict__ w_a1,  const float* __restrict__ b_a1,
    const float* __restrict__ w_a2,  const float* __restrict__ b_a2,
    const float* __restrict__ emb,   const float* __restrict__ w_seg,
    float* ws) {
  __shared__ float smem[13932];            // 13824 stage + 108 partials
  int* bar = (int*)(ws + WS_BAR);
  const int t   = threadIdx.x;
  const int blk = blockIdx.x;

  // ---- P0: GN stats partials (per 13824-float chunk) + L3 weight prefetch
  {
    const float4* p = (const float4*)(x_e + (size_t)blk * 13824);
    float s = 0.f, ss = 0.f;
    for (int i = t; i < 3456; i += 256) {
      float4 v = p[i];
      s  += v.x + v.y + v.z + v.w;
      ss += v.x*v.x + v.y*v.y + v.z*v.z + v.w*v.w;
    }
    #pragma unroll
    for (int off = 32; off; off >>= 1) {
      s  += __shfl_down(s, off);
      ss += __shfl_down(ss, off);
    }
    if ((t & 63) == 0) { smem[(t >> 6) * 2] = s; smem[(t >> 6) * 2 + 1] = ss; }
    // prefetch downstream weights into L2/L3 (overlaps with stats stream)
    float sink = 0.f;
    int tid = blk * 256 + t;               // 0..65535
    const float4* g4 = (const float4*)gap_w;             // 221184 f4
    for (int i = tid; i < 221184; i += 65536) { float4 v = g4[i]; sink += v.x + v.w; }
    if (tid < 65536) { float4 v = ((const float4*)w_cf)[tid]; sink += v.x + v.w; }
    if (tid < 32768) { float4 v = ((const float4*)w_c)[tid];  sink += v.x + v.w; }
    if (tid < 1024)  { float4 v = ((const float4*)w_a1)[tid]; sink += v.x; }
    if (tid < 192)   { float4 v = ((const float4*)emb)[tid];  sink += v.x; }
    __syncthreads();
    if (t == 0) {
      float2 r;
      r.x = smem[0] + smem[2] + smem[4] + smem[6];
      r.y = smem[1] + smem[3] + smem[5] + smem[7];
      ((float2*)(ws + WS_STATSPART))[blk] = r;
    }
    if (sink == 1.2345e30f) ws[WS_SINK] = sink;   // never taken; keeps loads live
  }
  spin_barrier(bar, 256);

  // ---- P1: GN+ReLU full channel in LDS, 27 window sums --------------------
  {
    int b = blk >> 7, c = blk & 127;
    int bg = b * 16 + (c >> 3);
    const float2* sp = (const float2*)(ws + WS_STATSPART) + bg * 8;
    float S = 0.f, SS = 0.f;
    #pragma unroll
    for (int j = 0; j < 8; j++) { float2 r = sp[j]; S += r.x; SS += r.y; }
    float mu   = S * (1.f / 110592.f);
    float var  = SS * (1.f / 110592.f) - mu * mu;
    float rstd = rsqrtf(var + 1e-5f);
    float ga = gn_g[c] * rstd;
    float be = gn_b[c] - mu * ga;

    const float4* p = (const float4*)(x_e + (size_t)blk * 13824);
    float4* l4 = (float4*)smem;
    for (int i = t; i < 3456; i += 256) {
      float4 v = p[i];
      float4 r;
      r.x = fmaxf(v.x * ga + be, 0.f);
      r.y = fmaxf(v.y * ga + be, 0.f);
      r.z = fmaxf(v.z * ga + be, 0.f);
      r.w = fmaxf(v.w * ga + be, 0.f);
      l4[i] = r;
    }
    __syncthreads();

    float acc[27];
    #pragma unroll
    for (int k = 0; k < 27; k++) acc[k] = 0.f;
    for (int pidx = t; pidx < 1331; pidx += 256) {
      int z = pidx / 121, rem = pidx % 121;
      int y = rem / 11, xx = rem % 11;
      int base = z * 1152 + y * 48 + xx * 2;
      #pragma unroll
      for (int kz = 0; kz < 3; kz++)
        #pragma unroll
        for (int ky = 0; ky < 3; ky++)
          #pragma unroll
          for (int kx = 0; kx < 3; kx++)
            acc[kz * 9 + ky * 3 + kx] += smem[base + kz * 576 + ky * 24 + kx];
    }
    #pragma unroll
    for (int k = 0; k < 27; k++)
      for (int off = 32; off; off >>= 1)
        acc[k] += __shfl_down(acc[k], off);
    float* part = smem + 13824;            // disjoint from stage
    int wid = t >> 6, lane = t & 63;
    if (lane == 0)
      #pragma unroll
      for (int k = 0; k < 27; k++) part[wid * 27 + k] = acc[k];
    __syncthreads();
    if (t < 27)
      ws[WS_WINS + blk * 27 + t] = part[t] + part[27 + t] + part[54 + t] + part[81 + t];
  }
  spin_barrier(bar, 256);

  // ---- P2: x_feat[b,o] = dot(wins[b], gap_w[o])/1331 + gap_b[o] -----------
  if (blk < 128) {
    int b = blk >> 6, oc = blk & 63;       // 64 chunks of 4 outputs
    const float* wp = ws + WS_WINS + b * 3456;
    for (int i = t; i < 3456; i += 256) smem[i] = wp[i];
    __syncthreads();
    int o = oc * 4 + (t >> 6), lane = t & 63;
    const float4* w4 = (const float4*)(gap_w + (size_t)o * 3456);
    const float4* s4 = (const float4*)smem;
    float acc = 0.f;
    for (int i = lane; i < 864; i += 64) {
      float4 wv = w4[i], sv = s4[i];
      acc += wv.x * sv.x + wv.y * sv.y + wv.z * sv.z + wv.w * sv.w;
    }
    #pragma unroll
    for (int off = 32; off; off >>= 1) acc += __shfl_down(acc, off);
    if (lane == 0) ws[WS_XF + b * 256 + o] = acc * (1.f / 1331.f) + gap_b[o];
  }
  spin_barrier(bar, 256);

  // ---- P3: p[bk,o] = relu(W_cf[o] . [xf[b];emb[k]] + b_cf[o]) -------------
  if (blk < 128) {
    for (int i = t; i < 1280; i += 256)
      smem[i] = (i < 512) ? ws[WS_XF + i] : emb[i - 512];
    __syncthreads();
    int o = blk * 4 + (t >> 6), lane = t & 63;
    const float4* w4  = (const float4*)(w_cf + (size_t)o * 512);
    const float4* xf4 = (const float4*)smem;          // [2][64] f4
    const float4* em4 = (const float4*)(smem + 512);  // [3][64] f4
    float4 wlo = w4[lane], whi = w4[lane + 64];
    float acc[6];
    #pragma unroll
    for (int bk = 0; bk < 6; bk++) {
      int b = (bk >= 3), k = bk - b * 3;
      float4 xv = xf4[b * 64 + lane];
      float4 ev = em4[k * 64 + lane];
      acc[bk] = wlo.x*xv.x + wlo.y*xv.y + wlo.z*xv.z + wlo.w*xv.w
              + whi.x*ev.x + whi.y*ev.y + whi.z*ev.z + whi.w*ev.w;
    }
    #pragma unroll
    for (int bk = 0; bk < 6; bk++)
      #pragma unroll
      for (int off = 32; off; off >>= 1)
        acc[bk] += __shfl_down(acc[bk], off);
    if (lane == 0) {
      float bb = b_cf[o];
      #pragma unroll
      for (int bk = 0; bk < 6; bk++)
        ws[WS_P + bk * 512 + o] = fmaxf(acc[bk] + bb, 0.f);
    }
  }
  spin_barrier(bar, 256);

  // ---- P4: c[bk,o] = W_c[o] . p[bk] + b_c[o] ------------------------------
  if (blk < 128) {
    for (int i = t; i < 3072; i += 256) smem[i] = ws[WS_P + i];
    __syncthreads();
    if (t < 128) {
      int o = blk * 2 + (t >> 6), lane = t & 63;
      const float4* w4 = (const float4*)(w_c + (size_t)o * 512);
      const float4* p4 = (const float4*)smem;         // [6][128] f4
      float4 wlo = w4[lane], whi = w4[lane + 64];
      float acc[6];
      #pragma unroll
      for (int bk = 0; bk < 6; bk++) {
        float4 plo = p4[bk * 128 + lane];
        float4 phi = p4[bk * 128 + lane + 64];
        acc[bk] = wlo.x*plo.x + wlo.y*plo.y + wlo.z*plo.z + wlo.w*plo.w
                + whi.x*phi.x + whi.y*phi.y + whi.z*phi.z + whi.w*phi.w;
      }
      #pragma unroll
      for (int bk = 0; bk < 6; bk++)
        #pragma unroll
        for (int off = 32; off; off >>= 1)
          acc[bk] += __shfl_down(acc[bk], off);
      if (lane == 0) {
        float bb = b_c[o];
        #pragma unroll
        for (int bk = 0; bk < 6; bk++)
          ws[WS_C + bk * 256 + o] = acc[bk] + bb;
      }
    }
  }
  spin_barrier(bar, 256);

  // ---- P5: attention MLP + effw (block 0) ---------------------------------
  if (blk == 0) {
    for (int i = t; i < 1536; i += 256) smem[i] = ws[WS_C + i];
    __syncthreads();
    float* hid = smem + 1536;              // [6][16]
    if (t < 96) {
      int bk = t >> 4, h = t & 15;
      const float4* w4 = (const float4*)(w_a1 + h * 256);
      const float4* c4 = (const float4*)(smem + bk * 256);
      float acc = b_a1[h];
      for (int j = 0; j < 64; j++) {
        float4 wv = w4[j], cv = c4[j];
        acc += wv.x*cv.x + wv.y*cv.y + wv.z*cv.z + wv.w*cv.w;
      }
      hid[bk * 16 + h] = fmaxf(acc, 0.f);
    }
    __syncthreads();
    if (t < 192) {
      int bk = t >> 5, o = t & 31;
      int k = bk - (bk >= 3) * 3;
      float acc = b_a2[o];
      #pragma unroll
      for (int j = 0; j < 16; j++) acc += w_a2[o * 16 + j] * hid[bk * 16 + j];
      float gate = 1.f / (1.f + __expf(-acc));
      ws[WS_EFFW + bk * 32 + o] = gate * w_seg[k * 32 + o];
    }
  }
}

// ---------------------------------------------------------------------------
// K_B: out[b,k,p] = sum_c effw[b,k,c]*pred[b,c,p] + b_seg[k].  1728 blocks.
// ---------------------------------------------------------------------------
__global__ __launch_bounds__(256) void seg_kernel(
    const float* __restrict__ pred, const float* __restrict__ ws_in,
    const float* __restrict__ b_seg, float* __restrict__ out) {
  __shared__ float ew[192];
  if (threadIdx.x < 192) ew[threadIdx.x] = ws_in[WS_EFFW + threadIdx.x];
  __syncthreads();
  int gid = blockIdx.x * 256 + threadIdx.x;     // < 442368 exactly
  int b = gid / P4;
  int p = gid - b * P4;
  const float4* pr = (const float4*)pred + (size_t)b * 32 * P4 + p;
  const float* e = ew + b * 96;
  v4f a0 = {0, 0, 0, 0}, a1 = a0, a2 = a0;
  #pragma unroll 8
  for (int c = 0; c < 32; c++) {
    float4 v = pr[(size_t)c * P4];
    float w0 = e[c], w1 = e[32 + c], w2 = e[64 + c];
    a0.x += w0 * v.x; a0.y += w0 * v.y; a0.z += w0 * v.z; a0.w += w0 * v.w;
    a1.x += w1 * v.x; a1.y += w1 * v.y; a1.z += w1 * v.z; a1.w += w1 * v.w;
    a2.x += w2 * v.x; a2.y += w2 * v.y; a2.z += w2 * v.z; a2.w += w2 * v.w;
  }
  float s0 = b_seg[0], s1 = b_seg[1], s2 = b_seg[2];
  a0 += s0;
  a1 += s1;
  a2 += s2;
  v4f* o4 = (v4f*)out + (size_t)b * 3 * P4 + p;
  __builtin_nontemporal_store(a0, o4);
  __builtin_nontemporal_store(a1, o4 + P4);
  __builtin_nontemporal_store(a2, o4 + 2 * P4);
}

extern "C" void kernel_launch(void* const* d_in, const int* in_sizes, int n_in,
                              void* d_out, int out_size, void* d_ws, size_t ws_size,
                              hipStream_t stream) {
  const float* x_e   = (const float*)d_in[0];
  const float* pred  = (const float*)d_in[1];
  const float* gn_g  = (const float*)d_in[2];
  const float* gn_b  = (const float*)d_in[3];
  const float* gap_w = (const float*)d_in[4];
  const float* gap_b = (const float*)d_in[5];
  const float* w_cf  = (const float*)d_in[6];
  const float* b_cf  = (const float*)d_in[7];
  const float* w_c   = (const float*)d_in[8];
  const float* b_c   = (const float*)d_in[9];
  const float* w_a1  = (const float*)d_in[10];
  const float* b_a1  = (const float*)d_in[11];
  const float* w_a2  = (const float*)d_in[12];
  const float* b_a2  = (const float*)d_in[13];
  const float* emb   = (const float*)d_in[14];
  const float* w_seg = (const float*)d_in[15];
  const float* b_seg = (const float*)d_in[16];
  float* ws  = (float*)d_ws;
  float* out = (float*)d_out;

  // zero the spin-barrier state (count+generation) each call/replay
  (void)hipMemsetAsync((char*)d_ws + WS_BAR * 4, 0, 8, stream);
  chain_kernel<<<256, 256, 0, stream>>>(x_e, gn_g, gn_b, gap_w, gap_b,
                                        w_cf, b_cf, w_c, b_c, w_a1, b_a1,
                                        w_a2, b_a2, emb, w_seg, ws);
  seg_kernel<<<1728, 256, 0, stream>>>(pred, ws, b_seg, out);
}

// Round 8
// 164.972 us; speedup vs baseline: 1.0460x; 1.0460x over previous
//
#include <hip/hip_runtime.h>
#include <hip/hip_bf16.h>

// ---------------------------------------------------------------------------
//   x_e  [2,128,24,24,24]   pred [2,32,96,96,96]   out [2,3,96,96,96] fp32
//   conv(128->256,k3,s2,VALID) -> 11^3 positions; mean∘conv commutes, so
//   conv+pool collapses to 27 window-sums per channel (exact).
//   K_A (256 blocks): P0 stats+prefetch -> group-spin -> P1 winsum -> gbar ->
//                     P2 xfeat -> gbar -> P3 ctrl tail (6 blocks, block-local)
//   K_B (1728 blocks): seg streaming op.
//   Sync via agent-scope atomics: arrivals = one RELEASE fetch_add; polling =
//   RELAXED loads (coherent, no RMW serialization), ACQUIRE load on exit.
// ---------------------------------------------------------------------------

#define P4 221184        // 96^3/4

typedef float v4f __attribute__((ext_vector_type(4)));

// ws float offsets
#define WS_STATSPART 0       // 256 x float2 = 512 floats
#define WS_WINS      512     // [2][128][27] = 6912
#define WS_XF        7424    // 512
#define WS_EFFW      7936    // 192
#define WS_SYNC_F    8128    // 34 ints: [0..31] group counters, [32] cnt, [33] gen
#define WS_SINK      8162

#define AGENT __HIP_MEMORY_SCOPE_AGENT

// Global barrier among nb co-resident blocks. cnt self-resets; gen grows.
__device__ __forceinline__ void gbar(int* sync, int nb) {
  __syncthreads();
  if (threadIdx.x == 0) {
    int* cnt = sync + 32;
    int* gen = sync + 33;
    int g = __hip_atomic_load(gen, __ATOMIC_RELAXED, AGENT);
    int old = __hip_atomic_fetch_add(cnt, 1, __ATOMIC_ACQ_REL, AGENT);
    if (old == nb - 1) {
      __hip_atomic_store(cnt, 0, __ATOMIC_RELAXED, AGENT);
      __hip_atomic_fetch_add(gen, 1, __ATOMIC_ACQ_REL, AGENT);
    } else {
      while (__hip_atomic_load(gen, __ATOMIC_RELAXED, AGENT) == g)
        __builtin_amdgcn_s_sleep(16);
      (void)__hip_atomic_load(gen, __ATOMIC_ACQUIRE, AGENT);   // acquire fence
    }
  }
  __syncthreads();
}

// ---------------------------------------------------------------------------
// K_A: pre-chain on 256 blocks (1/CU guaranteed resident: 55 KB LDS).
// Stats chunk blk == channel slice (b,c)=blk (13824 floats at x_e+blk*13824).
// ---------------------------------------------------------------------------
__global__ __launch_bounds__(256) void chain_kernel(
    const float* __restrict__ x_e,
    const float* __restrict__ gn_g, const float* __restrict__ gn_b,
    const float* __restrict__ gap_w, const float* __restrict__ gap_b,
    const float* __restrict__ w_cf,  const float* __restrict__ b_cf,
    const float* __restrict__ w_c,   const float* __restrict__ b_c,
    const float* __restrict__ w_a1,  const float* __restrict__ b_a1,
    const float* __restrict__ w_a2,  const float* __restrict__ b_a2,
    const float* __restrict__ emb,   const float* __restrict__ w_seg,
    float* ws) {
  __shared__ float smem[13932];            // 13824 stage + 108 partials
  int* sync = (int*)(ws + WS_SYNC_F);
  const int t   = threadIdx.x;
  const int blk = blockIdx.x;

  // ---- P0: per-channel GN stats partial + L3 weight prefetch --------------
  {
    const float4* p = (const float4*)(x_e + (size_t)blk * 13824);
    float s = 0.f, ss = 0.f;
    for (int i = t; i < 3456; i += 256) {
      float4 v = p[i];
      s  += v.x + v.y + v.z + v.w;
      ss += v.x*v.x + v.y*v.y + v.z*v.z + v.w*v.w;
    }
    #pragma unroll
    for (int off = 32; off; off >>= 1) {
      s  += __shfl_down(s, off);
      ss += __shfl_down(ss, off);
    }
    if ((t & 63) == 0) { smem[(t >> 6) * 2] = s; smem[(t >> 6) * 2 + 1] = ss; }
    // prefetch downstream weights into L2/L3 (overlaps with stats stream)
    float sink = 0.f;
    int tid = blk * 256 + t;               // 0..65535
    const float4* g4 = (const float4*)gap_w;             // 221184 f4
    for (int i = tid; i < 221184; i += 65536) { float4 v = g4[i]; sink += v.x + v.w; }
    if (tid < 65536) { float4 v = ((const float4*)w_cf)[tid]; sink += v.x + v.w; }
    if (tid < 32768) { float4 v = ((const float4*)w_c)[tid];  sink += v.x + v.w; }
    if (tid < 1024)  { float4 v = ((const float4*)w_a1)[tid]; sink += v.x; }
    if (tid < 192)   { float4 v = ((const float4*)emb)[tid];  sink += v.x; }
    if (sink == 1.2345e30f) ws[WS_SINK] = sink;   // never taken; keeps loads live
    __syncthreads();
    if (t == 0) {
      float2 r;
      r.x = smem[0] + smem[2] + smem[4] + smem[6];
      r.y = smem[1] + smem[3] + smem[5] + smem[7];
      ((float2*)(ws + WS_STATSPART))[blk] = r;
      // group micro-spin: 8 channel-blocks per group counter
      int grp = blk >> 3;
      __hip_atomic_fetch_add(&sync[grp], 1, __ATOMIC_ACQ_REL, AGENT);
      while (__hip_atomic_load(&sync[grp], __ATOMIC_RELAXED, AGENT) < 8)
        __builtin_amdgcn_s_sleep(8);
      (void)__hip_atomic_load(&sync[grp], __ATOMIC_ACQUIRE, AGENT);
    }
    __syncthreads();
  }

  // ---- P1: GN+ReLU full channel in LDS, 27 window sums --------------------
  {
    int c = blk & 127;
    const float2* sp = ((const float2*)(ws + WS_STATSPART)) + (blk & ~7);
    float S = 0.f, SS = 0.f;
    #pragma unroll
    for (int j = 0; j < 8; j++) { float2 r = sp[j]; S += r.x; SS += r.y; }
    float mu   = S * (1.f / 110592.f);
    float var  = SS * (1.f / 110592.f) - mu * mu;
    float rstd = rsqrtf(var + 1e-5f);
    float ga = gn_g[c] * rstd;
    float be = gn_b[c] - mu * ga;

    const float4* p = (const float4*)(x_e + (size_t)blk * 13824);
    float4* l4 = (float4*)smem;
    for (int i = t; i < 3456; i += 256) {
      float4 v = p[i];
      float4 r;
      r.x = fmaxf(v.x * ga + be, 0.f);
      r.y = fmaxf(v.y * ga + be, 0.f);
      r.z = fmaxf(v.z * ga + be, 0.f);
      r.w = fmaxf(v.w * ga + be, 0.f);
      l4[i] = r;
    }
    __syncthreads();

    float acc[27];
    #pragma unroll
    for (int k = 0; k < 27; k++) acc[k] = 0.f;
    for (int pidx = t; pidx < 1331; pidx += 256) {
      int z = pidx / 121, rem = pidx % 121;
      int y = rem / 11, xx = rem % 11;
      int base = z * 1152 + y * 48 + xx * 2;
      #pragma unroll
      for (int kz = 0; kz < 3; kz++)
        #pragma unroll
        for (int ky = 0; ky < 3; ky++)
          #pragma unroll
          for (int kx = 0; kx < 3; kx++)
            acc[kz * 9 + ky * 3 + kx] += smem[base + kz * 576 + ky * 24 + kx];
    }
    #pragma unroll
    for (int k = 0; k < 27; k++)
      for (int off = 32; off; off >>= 1)
        acc[k] += __shfl_down(acc[k], off);
    float* part = smem + 13824;            // disjoint from stage
    int wid = t >> 6, lane = t & 63;
    if (lane == 0)
      #pragma unroll
      for (int k = 0; k < 27; k++) part[wid * 27 + k] = acc[k];
    __syncthreads();
    if (t < 27)
      ws[WS_WINS + blk * 27 + t] = part[t] + part[27 + t] + part[54 + t] + part[81 + t];
  }
  gbar(sync, 256);

  // ---- P2: x_feat[b,o] = dot(wins[b], gap_w[o])/1331 + gap_b[o] -----------
  if (blk < 128) {
    int b = blk >> 6, oc = blk & 63;       // 64 chunks of 4 outputs
    const float* wp = ws + WS_WINS + b * 3456;
    for (int i = t; i < 3456; i += 256) smem[i] = wp[i];
    __syncthreads();
    int o = oc * 4 + (t >> 6), lane = t & 63;
    const float4* w4 = (const float4*)(gap_w + (size_t)o * 3456);
    const float4* s4 = (const float4*)smem;
    float acc = 0.f;
    for (int i = lane; i < 864; i += 64) {
      float4 wv = w4[i], sv = s4[i];
      acc += wv.x * sv.x + wv.y * sv.y + wv.z * sv.z + wv.w * sv.w;
    }
    #pragma unroll
    for (int off = 32; off; off >>= 1) acc += __shfl_down(acc, off);
    if (lane == 0) ws[WS_XF + b * 256 + o] = acc * (1.f / 1331.f) + gap_b[o];
  }
  gbar(sync, 256);

  // ---- P3: whole controller tail, block-local per (b,k) -------------------
  if (blk < 6) {
    int b = blk / 3, k = blk % 3;
    float* cond = smem;                    // 512
    float* pbuf = smem + 512;              // 512
    float* cbuf = smem + 1024;             // 256
    float* hid  = smem + 1280;             // 16
    for (int i = t; i < 512; i += 256)
      cond[i] = (i < 256) ? ws[WS_XF + b * 256 + i] : emb[k * 256 + (i - 256)];
    __syncthreads();
    // p[o] = relu(w_cf[o].cond + b_cf[o]); each thread does o=t and o=t+256
    #pragma unroll
    for (int half = 0; half < 2; half++) {
      int o = t + half * 256;
      const float4* w4 = (const float4*)(w_cf + (size_t)o * 512);
      const float4* c4 = (const float4*)cond;
      float acc = 0.f;
      #pragma unroll 8
      for (int j = 0; j < 128; j++) {
        float4 wv = w4[j], cv = c4[j];
        acc += wv.x*cv.x + wv.y*cv.y + wv.z*cv.z + wv.w*cv.w;
      }
      pbuf[o] = fmaxf(acc + b_cf[o], 0.f);
    }
    __syncthreads();
    // c[o=t] = w_c[t].p + b_c[t]
    {
      const float4* w4 = (const float4*)(w_c + (size_t)t * 512);
      const float4* p4 = (const float4*)pbuf;
      float acc = 0.f;
      #pragma unroll 8
      for (int j = 0; j < 128; j++) {
        float4 wv = w4[j], pv = p4[j];
        acc += wv.x*pv.x + wv.y*pv.y + wv.z*pv.z + wv.w*pv.w;
      }
      cbuf[t] = acc + b_c[t];
    }
    __syncthreads();
    if (t < 16) {
      const float4* w4 = (const float4*)(w_a1 + t * 256);
      const float4* c4 = (const float4*)cbuf;
      float acc = b_a1[t];
      for (int j = 0; j < 64; j++) {
        float4 wv = w4[j], cv = c4[j];
        acc += wv.x*cv.x + wv.y*cv.y + wv.z*cv.z + wv.w*cv.w;
      }
      hid[t] = fmaxf(acc, 0.f);
    }
    __syncthreads();
    if (t < 32) {
      float acc = b_a2[t];
      #pragma unroll
      for (int j = 0; j < 16; j++) acc += w_a2[t * 16 + j] * hid[j];
      float gate = 1.f / (1.f + __expf(-acc));
      ws[WS_EFFW + blk * 32 + t] = gate * w_seg[k * 32 + t];
    }
  }
}

// ---------------------------------------------------------------------------
// K_B: out[b,k,p] = sum_c effw[b,k,c]*pred[b,c,p] + b_seg[k].  1728 blocks.
// ---------------------------------------------------------------------------
__global__ __launch_bounds__(256) void seg_kernel(
    const float* __restrict__ pred, const float* __restrict__ ws_in,
    const float* __restrict__ b_seg, float* __restrict__ out) {
  __shared__ float ew[192];
  if (threadIdx.x < 192) ew[threadIdx.x] = ws_in[WS_EFFW + threadIdx.x];
  __syncthreads();
  int gid = blockIdx.x * 256 + threadIdx.x;     // < 442368 exactly
  int b = gid / P4;
  int p = gid - b * P4;
  const float4* pr = (const float4*)pred + (size_t)b * 32 * P4 + p;
  const float* e = ew + b * 96;
  v4f a0 = {0, 0, 0, 0}, a1 = a0, a2 = a0;
  #pragma unroll 8
  for (int c = 0; c < 32; c++) {
    float4 v = pr[(size_t)c * P4];
    float w0 = e[c], w1 = e[32 + c], w2 = e[64 + c];
    a0.x += w0 * v.x; a0.y += w0 * v.y; a0.z += w0 * v.z; a0.w += w0 * v.w;
    a1.x += w1 * v.x; a1.y += w1 * v.y; a1.z += w1 * v.z; a1.w += w1 * v.w;
    a2.x += w2 * v.x; a2.y += w2 * v.y; a2.z += w2 * v.z; a2.w += w2 * v.w;
  }
  float s0 = b_seg[0], s1 = b_seg[1], s2 = b_seg[2];
  a0 += s0;
  a1 += s1;
  a2 += s2;
  v4f* o4 = (v4f*)out + (size_t)b * 3 * P4 + p;
  __builtin_nontemporal_store(a0, o4);
  __builtin_nontemporal_store(a1, o4 + P4);
  __builtin_nontemporal_store(a2, o4 + 2 * P4);
}

extern "C" void kernel_launch(void* const* d_in, const int* in_sizes, int n_in,
                              void* d_out, int out_size, void* d_ws, size_t ws_size,
                              hipStream_t stream) {
  const float* x_e   = (const float*)d_in[0];
  const float* pred  = (const float*)d_in[1];
  const float* gn_g  = (const float*)d_in[2];
  const float* gn_b  = (const float*)d_in[3];
  const float* gap_w = (const float*)d_in[4];
  const float* gap_b = (const float*)d_in[5];
  const float* w_cf  = (const float*)d_in[6];
  const float* b_cf  = (const float*)d_in[7];
  const float* w_c   = (const float*)d_in[8];
  const float* b_c   = (const float*)d_in[9];
  const float* w_a1  = (const float*)d_in[10];
  const float* b_a1  = (const float*)d_in[11];
  const float* w_a2  = (const float*)d_in[12];
  const float* b_a2  = (const float*)d_in[13];
  const float* emb   = (const float*)d_in[14];
  const float* w_seg = (const float*)d_in[15];
  const float* b_seg = (const float*)d_in[16];
  float* ws  = (float*)d_ws;
  float* out = (float*)d_out;

  // zero the 34-int sync area (group counters + barrier state) each replay
  (void)hipMemsetAsync((char*)d_ws + WS_SYNC_F * 4, 0, 34 * 4, stream);
  chain_kernel<<<256, 256, 0, stream>>>(x_e, gn_g, gn_b, gap_w, gap_b,
                                        w_cf, b_cf, w_c, b_c, w_a1, b_a1,
                                        w_a2, b_a2, emb, w_seg, ws);
  seg_kernel<<<1728, 256, 0, stream>>>(pred, ws, b_seg, out);
}

// Round 9
// 100.926 us; speedup vs baseline: 1.7098x; 1.6346x over previous
//
#include <hip/hip_runtime.h>
#include <hip/hip_bf16.h>

// ---------------------------------------------------------------------------
//   x_e  [2,128,24,24,24]   pred [2,32,96,96,96]   out [2,3,96,96,96] fp32
//   conv(128->256,k3,s2,VALID) -> 11^3 positions; mean∘conv commutes =>
//   conv+pool collapses to 27 window-sums per channel (exact).  Window sums
//   are separable: per-row E/O/E sums in x, then y, then z.
//   6 plain launches (no device-side sync — measured 10-25us/barrier on
//   gfx950; narrow-block weight reads measured ~40us/MB/CU):
//   K1 stats+prefetch(576) -> K2 winsum(256) -> K3 xfeat(128) ->
//   K4 ctrl1(24) -> K5 ctrl2(12) -> K6 ctrl3+seg(1728)
// ---------------------------------------------------------------------------

#define P4 221184        // 96^3/4

typedef float v4f __attribute__((ext_vector_type(4)));

// ws float offsets
#define WS_STATSPART 0       // 512 x float2 = 1024 floats
#define WS_WINS      1024    // [2][128][27] = 6912
#define WS_XF        7936    // 512
#define WS_P         8448    // 6*512 = 3072
#define WS_C         11520   // 6*256 = 1536
#define WS_SINK      13056

// ---------------------------------------------------------------------------
// K1: GN stats partials (blocks 0..511: (b*16+g)*16+chunk over 6912 floats)
//     + L3 weight prefetch (blocks 512..575).
// ---------------------------------------------------------------------------
__global__ __launch_bounds__(256) void k1_stats(
    const float* __restrict__ x, const float* __restrict__ gap_w,
    const float* __restrict__ w_cf, const float* __restrict__ w_c,
    const float* __restrict__ w_a1, const float* __restrict__ emb,
    float* __restrict__ ws) {
  if (blockIdx.x >= 512) {
    float s = 0.f;
    int tid = (blockIdx.x - 512) * 256 + threadIdx.x;   // 0..16383
    const float4* g4 = (const float4*)gap_w;            // 221184 f4
    for (int i = tid; i < 221184; i += 16384) { float4 v = g4[i]; s += v.x + v.w; }
    const float4* a4 = (const float4*)w_cf;             // 65536 f4
    for (int i = tid; i < 65536;  i += 16384) { float4 v = a4[i]; s += v.x + v.w; }
    const float4* c4 = (const float4*)w_c;              // 32768 f4
    for (int i = tid; i < 32768;  i += 16384) { float4 v = c4[i]; s += v.x + v.w; }
    if (tid < 1024) { float4 v = ((const float4*)w_a1)[tid]; s += v.x; }
    if (tid < 192)  { float4 v = ((const float4*)emb)[tid];  s += v.x; }
    if (s == 1.2345e30f) ws[WS_SINK] = s;   // never taken; keeps loads live
    return;
  }
  int blk = blockIdx.x;                     // bg*16 + chunk
  const float4* p = (const float4*)(x + (size_t)blk * 6912);
  float s = 0.f, ss = 0.f;
  for (int i = threadIdx.x; i < 1728; i += 256) {
    float4 v = p[i];
    s  += v.x + v.y + v.z + v.w;
    ss += v.x*v.x + v.y*v.y + v.z*v.z + v.w*v.w;
  }
  #pragma unroll
  for (int off = 32; off; off >>= 1) {
    s  += __shfl_down(s, off);
    ss += __shfl_down(ss, off);
  }
  __shared__ float a[4], b2[4];
  int wid = threadIdx.x >> 6, lane = threadIdx.x & 63;
  if (lane == 0) { a[wid] = s; b2[wid] = ss; }
  __syncthreads();
  if (threadIdx.x == 0) {
    float2 r;
    r.x = a[0] + a[1] + a[2] + a[3];
    r.y = b2[0] + b2[1] + b2[2] + b2[3];
    ((float2*)(ws + WS_STATSPART))[blk] = r;
  }
}

// ---------------------------------------------------------------------------
// K2: per-(b,c) GN+ReLU staged in LDS, separable 27 window sums. 256 blocks.
//   passA: per (zz,yy) row -> 3 x-sums (E1,O,E2)
//   passB: per (zz,kx)     -> 3 y-sums
//   passC: per (ky,kx)     -> 3 z-sums -> wins[blk*27 + kz*9+ky*3+kx]
// ---------------------------------------------------------------------------
__global__ __launch_bounds__(256) void k2_winsum(
    const float* __restrict__ x, const float* __restrict__ gn_g,
    const float* __restrict__ gn_b, float* __restrict__ ws) {
  __shared__ float stage[13824];   // [zz][yy][xx]
  __shared__ float sx[1728];       // [zz*24+yy][3]
  __shared__ float sxy[216];       // [zz][ky*3+kx]
  int blk = blockIdx.x;
  int c = blk & 127;
  int bg = (blk >> 7) * 16 + (c >> 3);
  const float2* sp = (const float2*)(ws + WS_STATSPART) + bg * 16;
  float S = 0.f, SS = 0.f;
  #pragma unroll
  for (int j = 0; j < 16; j++) { float2 r = sp[j]; S += r.x; SS += r.y; }
  float mu   = S * (1.f / 110592.f);
  float var  = SS * (1.f / 110592.f) - mu * mu;
  float rstd = rsqrtf(var + 1e-5f);
  float ga = gn_g[c] * rstd;
  float be = gn_b[c] - mu * ga;

  int t = threadIdx.x;
  const float4* p = (const float4*)(x + (size_t)blk * 13824);
  float4* l4 = (float4*)stage;
  for (int i = t; i < 3456; i += 256) {
    float4 v = p[i];
    float4 r;
    r.x = fmaxf(v.x * ga + be, 0.f);
    r.y = fmaxf(v.y * ga + be, 0.f);
    r.z = fmaxf(v.z * ga + be, 0.f);
    r.w = fmaxf(v.w * ga + be, 0.f);
    l4[i] = r;
  }
  __syncthreads();

  // pass A: 576 rows
  for (int r = t; r < 576; r += 256) {
    const float* v = stage + r * 24;
    float e1 = 0.f, o = 0.f, e2 = 0.f;
    #pragma unroll
    for (int xx = 0; xx < 11; xx++) {
      e1 += v[2 * xx];
      o  += v[2 * xx + 1];
      e2 += v[2 * xx + 2];
    }
    sx[r * 3 + 0] = e1;
    sx[r * 3 + 1] = o;
    sx[r * 3 + 2] = e2;
  }
  __syncthreads();

  // pass B: 72 tasks (zz,kx)
  if (t < 72) {
    int zz = t / 3, kx = t % 3;
    const float* v = sx + zz * 72 + kx;   // stride 3 over yy
    float e1 = 0.f, o = 0.f, e2 = 0.f;
    #pragma unroll
    for (int yy = 0; yy < 11; yy++) {
      e1 += v[3 * (2 * yy)];
      o  += v[3 * (2 * yy + 1)];
      e2 += v[3 * (2 * yy + 2)];
    }
    sxy[zz * 9 + 0 + kx] = e1;
    sxy[zz * 9 + 3 + kx] = o;
    sxy[zz * 9 + 6 + kx] = e2;
  }
  __syncthreads();

  // pass C: 9 tasks (ky,kx) -> 3 kz outputs each
  if (t < 9) {
    const float* v = sxy + t;             // stride 9 over zz
    float e1 = 0.f, o = 0.f, e2 = 0.f;
    #pragma unroll
    for (int zz = 0; zz < 11; zz++) {
      e1 += v[9 * (2 * zz)];
      o  += v[9 * (2 * zz + 1)];
      e2 += v[9 * (2 * zz + 2)];
    }
    ws[WS_WINS + blk * 27 + 0  + t] = e1;
    ws[WS_WINS + blk * 27 + 9  + t] = o;
    ws[WS_WINS + blk * 27 + 18 + t] = e2;
  }
}

// ---------------------------------------------------------------------------
// K3: x_feat[b,o] = dot(wins[b], gap_w[o])/1331 + gap_b[o].  128 blocks.
// ---------------------------------------------------------------------------
__global__ __launch_bounds__(256) void k3_xfeat(
    const float* __restrict__ ws_in, const float* __restrict__ gap_w,
    const float* __restrict__ gap_b, float* __restrict__ ws_out) {
  __shared__ float sl[3456];
  int b = blockIdx.x >> 6, oc = blockIdx.x & 63;   // 64 chunks of 4 outputs
  int t = threadIdx.x;
  const float* wp = ws_in + WS_WINS + b * 3456;
  for (int i = t; i < 3456; i += 256) sl[i] = wp[i];
  __syncthreads();
  int o = oc * 4 + (t >> 6), lane = t & 63;
  const float4* w4 = (const float4*)(gap_w + (size_t)o * 3456);
  const float4* s4 = (const float4*)sl;
  float acc = 0.f;
  for (int i = lane; i < 864; i += 64) {
    float4 wv = w4[i], sv = s4[i];
    acc += wv.x * sv.x + wv.y * sv.y + wv.z * sv.z + wv.w * sv.w;
  }
  #pragma unroll
  for (int off = 32; off; off >>= 1) acc += __shfl_down(acc, off);
  if (lane == 0) ws_out[WS_XF + b * 256 + o] = acc * (1.f / 1331.f) + gap_b[o];
}

// ---------------------------------------------------------------------------
// K4: p[bk,o] = relu(W_cf . cond + b_cf).  24 blocks = bk*4 + q.
// ---------------------------------------------------------------------------
__global__ __launch_bounds__(256) void k4_ctrl1(
    const float* __restrict__ ws_in, const float* __restrict__ emb,
    const float* __restrict__ w_cf, const float* __restrict__ b_cf,
    float* __restrict__ ws_out) {
  int bk = blockIdx.x >> 2;
  int q = blockIdx.x & 3;
  int b = bk / 3, k = bk % 3;
  __shared__ float cond[512];
  __shared__ float ph[256];
  int t = threadIdx.x;
  for (int i = t; i < 512; i += 256)
    cond[i] = (i < 256) ? ws_in[WS_XF + b * 256 + i] : emb[k * 256 + (i - 256)];
  __syncthreads();
  int ol = t & 127, half = t >> 7;
  int o = q * 128 + ol;
  const float4* w4 = (const float4*)(w_cf + (size_t)o * 512) + half * 64;
  const float4* c4 = (const float4*)cond + half * 64;
  float acc = 0.f;
  #pragma unroll 8
  for (int j = 0; j < 64; j++) {
    float4 wv = w4[j], cv = c4[j];
    acc += wv.x * cv.x + wv.y * cv.y + wv.z * cv.z + wv.w * cv.w;
  }
  ph[half * 128 + ol] = acc;
  __syncthreads();
  if (t < 128)
    ws_out[WS_P + bk * 512 + o] = fmaxf(ph[t] + ph[128 + t] + b_cf[o], 0.f);
}

// ---------------------------------------------------------------------------
// K5: c[bk,o] = W_c . p + b_c.  12 blocks = bk*2 + h.
// ---------------------------------------------------------------------------
__global__ __launch_bounds__(256) void k5_ctrl2(
    const float* __restrict__ ws_in, const float* __restrict__ w_c,
    const float* __restrict__ b_c, float* __restrict__ ws_out) {
  int bk = blockIdx.x >> 1;
  int h = blockIdx.x & 1;
  __shared__ float pbuf[512];
  __shared__ float ph[256];
  int t = threadIdx.x;
  for (int i = t; i < 512; i += 256) pbuf[i] = ws_in[WS_P + bk * 512 + i];
  __syncthreads();
  int ol = t & 127, half = t >> 7;
  int o = h * 128 + ol;
  const float4* w4 = (const float4*)(w_c + (size_t)o * 512) + half * 64;
  const float4* p4 = (const float4*)pbuf + half * 64;
  float acc = 0.f;
  #pragma unroll 8
  for (int j = 0; j < 64; j++) {
    float4 wv = w4[j], pv = p4[j];
    acc += wv.x * pv.x + wv.y * pv.y + wv.z * pv.z + wv.w * pv.w;
  }
  ph[half * 128 + ol] = acc;
  __syncthreads();
  if (t < 128)
    ws_out[WS_C + bk * 256 + o] = ph[t] + ph[128 + t] + b_c[o];
}

// ---------------------------------------------------------------------------
// K6: per-block redundant ctrl3 (attention MLP -> effw, ~23KB L2-hot reads),
//     then the streaming contraction.  1728 blocks.
// ---------------------------------------------------------------------------
__global__ __launch_bounds__(256) void k6_seg(
    const float* __restrict__ pred, const float* __restrict__ ws_in,
    const float* __restrict__ w_a1, const float* __restrict__ b_a1,
    const float* __restrict__ w_a2, const float* __restrict__ b_a2,
    const float* __restrict__ w_seg, const float* __restrict__ b_seg,
    float* __restrict__ out) {
  __shared__ float cl[1536];
  __shared__ float hid[96];
  __shared__ float ew[192];
  int t = threadIdx.x;
  for (int i = t; i < 1536; i += 256) cl[i] = ws_in[WS_C + i];
  __syncthreads();
  if (t < 96) {
    int bk = t >> 4, h = t & 15;
    const float4* w4 = (const float4*)(w_a1 + h * 256);
    const float4* c4 = (const float4*)(cl + bk * 256);
    float acc = b_a1[h];
    #pragma unroll 8
    for (int j = 0; j < 64; j++) {
      float4 wv = w4[j], cv = c4[j];
      acc += wv.x*cv.x + wv.y*cv.y + wv.z*cv.z + wv.w*cv.w;
    }
    hid[bk * 16 + h] = fmaxf(acc, 0.f);
  }
  __syncthreads();
  if (t < 192) {
    int bk = t >> 5, o = t & 31;
    int k = bk - (bk >= 3) * 3;
    float acc = b_a2[o];
    #pragma unroll
    for (int j = 0; j < 16; j++) acc += w_a2[o * 16 + j] * hid[bk * 16 + j];
    float gate = 1.f / (1.f + __expf(-acc));
    ew[bk * 32 + o] = gate * w_seg[k * 32 + o];
  }
  __syncthreads();

  int gid = blockIdx.x * 256 + t;               // < 442368 exactly
  int b = gid / P4;
  int p = gid - b * P4;
  const float4* pr = (const float4*)pred + (size_t)b * 32 * P4 + p;
  const float* e = ew + b * 96;
  v4f a0 = {0, 0, 0, 0}, a1 = a0, a2 = a0;
  #pragma unroll 8
  for (int c = 0; c < 32; c++) {
    float4 v = pr[(size_t)c * P4];
    float w0 = e[c], w1 = e[32 + c], w2 = e[64 + c];
    a0.x += w0 * v.x; a0.y += w0 * v.y; a0.z += w0 * v.z; a0.w += w0 * v.w;
    a1.x += w1 * v.x; a1.y += w1 * v.y; a1.z += w1 * v.z; a1.w += w1 * v.w;
    a2.x += w2 * v.x; a2.y += w2 * v.y; a2.z += w2 * v.z; a2.w += w2 * v.w;
  }
  a0 += b_seg[0];
  a1 += b_seg[1];
  a2 += b_seg[2];
  v4f* o4 = (v4f*)out + (size_t)b * 3 * P4 + p;
  __builtin_nontemporal_store(a0, o4);
  __builtin_nontemporal_store(a1, o4 + P4);
  __builtin_nontemporal_store(a2, o4 + 2 * P4);
}

extern "C" void kernel_launch(void* const* d_in, const int* in_sizes, int n_in,
                              void* d_out, int out_size, void* d_ws, size_t ws_size,
                              hipStream_t stream) {
  const float* x_e   = (const float*)d_in[0];
  const float* pred  = (const float*)d_in[1];
  const float* gn_g  = (const float*)d_in[2];
  const float* gn_b  = (const float*)d_in[3];
  const float* gap_w = (const float*)d_in[4];
  const float* gap_b = (const float*)d_in[5];
  const float* w_cf  = (const float*)d_in[6];
  const float* b_cf  = (const float*)d_in[7];
  const float* w_c   = (const float*)d_in[8];
  const float* b_c   = (const float*)d_in[9];
  const float* w_a1  = (const float*)d_in[10];
  const float* b_a1  = (const float*)d_in[11];
  const float* w_a2  = (const float*)d_in[12];
  const float* b_a2  = (const float*)d_in[13];
  const float* emb   = (const float*)d_in[14];
  const float* w_seg = (const float*)d_in[15];
  const float* b_seg = (const float*)d_in[16];
  float* ws  = (float*)d_ws;
  float* out = (float*)d_out;

  k1_stats<<<576, 256, 0, stream>>>(x_e, gap_w, w_cf, w_c, w_a1, emb, ws);
  k2_winsum<<<256, 256, 0, stream>>>(x_e, gn_g, gn_b, ws);
  k3_xfeat<<<128, 256, 0, stream>>>(ws, gap_w, gap_b, ws);
  k4_ctrl1<<<24, 256, 0, stream>>>(ws, emb, w_cf, b_cf, ws);
  k5_ctrl2<<<12, 256, 0, stream>>>(ws, w_c, b_c, ws);
  k6_seg<<<1728, 256, 0, stream>>>(pred, ws, w_a1, b_a1, w_a2, b_a2,
                                   w_seg, b_seg, out);
}